// Round 8
// baseline (259.112 us; speedup 1.0000x reference)
//
#include <hip/hip_runtime.h>
#include <hip/hip_bf16.h>

typedef __bf16 bf16x8 __attribute__((ext_vector_type(8)));
typedef float f32x4 __attribute__((ext_vector_type(4)));
typedef unsigned int u32;
typedef unsigned short u16;
typedef u32 u32x4 __attribute__((ext_vector_type(4)));
typedef u16 u16x4 __attribute__((ext_vector_type(4)));
typedef u16 u16x8 __attribute__((ext_vector_type(8)));

// manual RNE f32->bf16 (prep kernels)
__device__ __forceinline__ u16 f2bf(float x) {
  u32 u = __float_as_uint(x);
  return (u16)((u + 0x7FFFu + ((u >> 16) & 1u)) >> 16);
}
// compiler cast (hot path; lowers to v_cvt_pk_bf16_f32)
__device__ __forceinline__ u16 cvt_bf16(float x) {
  __bf16 h = (__bf16)x;
  return __builtin_bit_cast(u16, h);
}

__device__ __forceinline__ bf16x8 ld_frag_lds(const u16* base, int byteOff) {
  u32x4 v = *(const u32x4*)((const char*)base + byteOff);
  return __builtin_bit_cast(bf16x8, v);
}
__device__ __forceinline__ bf16x8 ld_frag_glb(const u16* p) {
  u32x4 v = *(const u32x4*)p;
  return __builtin_bit_cast(bf16x8, v);
}

// ---------------------------------------------------------------------------
// prep_w: bf16 MFMA A-operand (weight) fragments.
// wfA: Wcat = [W2a rows 0:64 (e1j) ; 64:128 (E2[j,i]) ; 192:256 (E2[i,j])]
//      K=192, N=256: wfA[((ntg*6+ks)*64+lane)*8+q] =
//        Wcat[ks*32+(lane>>4)*8+q][ntg*16+(lane&15)]
// wfB: W2b K=256 N=64: wfB[((ntg*8+ks)*64+lane)*8+q] likewise.
// ---------------------------------------------------------------------------
__global__ void prep_w_kernel(const float* __restrict__ W2a, const float* __restrict__ W2b,
                              u16* __restrict__ wfA, u16* __restrict__ wfB) {
  int t = blockIdx.x * 256 + threadIdx.x;
  if (t < 6144) {  // 16 ntg * 6 ks * 64 lanes
    int lane = t & 63;
    int ks = (t >> 6) % 6;
    int ntg = t / 384;
    int col = (ntg << 4) + (lane & 15);
    int kk = (ks << 5) + ((lane >> 4) << 3);
    int row = kk + (kk >= 128 ? 64 : 0);  // skip Wa2 rows 128:192 (handled by T2')
#pragma unroll
    for (int q = 0; q < 8; ++q)
      wfA[t * 8 + q] = f2bf(W2a[(row + q) * 256 + col]);
  } else if (t < 8192) {  // 4 ntg * 8 ks * 64 lanes
    int t2 = t - 6144;
    int lane = t2 & 63;
    int ks = (t2 >> 6) & 7;
    int ntg = t2 >> 9;
    int col = (ntg << 4) + (lane & 15);
    int k = (ks << 5) + ((lane >> 4) << 3);
#pragma unroll
    for (int q = 0; q < 8; ++q)
      wfB[t2 * 8 + q] = f2bf(W2b[(k + q) * 64 + col]);
  }
}

// ---------------------------------------------------------------------------
// prep_T2: T2p[b,i,n] = e1[b,i] @ W2a[128:192] + b2a[n]   (f32, 2 MB)
// ---------------------------------------------------------------------------
__global__ __launch_bounds__(256) void prep_T2_kernel(
    const float* __restrict__ emb1, const float* __restrict__ W2a,
    const float* __restrict__ b2a, float* __restrict__ T2p) {
  __shared__ float e1row[64];
  int bn = blockIdx.x;
  int t = threadIdx.x;
  if (t < 64) e1row[t] = emb1[bn * 64 + t];
  __syncthreads();
  float a = b2a[t];
#pragma unroll 8
  for (int k = 0; k < 64; ++k) a += e1row[k] * W2a[(128 + k) * 256 + t];
  T2p[(size_t)bn * 256 + t] = a;
}

// ---------------------------------------------------------------------------
// out1: R1-proven. One block per (b,i). Also serves to pre-warm emb2 into L3
// before out2's scattered gathers (launched first).
// ---------------------------------------------------------------------------
__global__ __launch_bounds__(256) void out1_kernel(
    const float* __restrict__ emb1, const float* __restrict__ emb2,
    const float* __restrict__ W1a, const float* __restrict__ b1a,
    const float* __restrict__ W1b, const float* __restrict__ b1b,
    float* __restrict__ out1) {
  int bi = blockIdx.x;
  int t = threadIdx.x;
  __shared__ float smax[4][64];
  __shared__ float smin[4][64];
  __shared__ float cat1[192];
  __shared__ float h[128];

  int d = t & 63, q = t >> 6;
  const float* base = emb2 + (size_t)bi * 256 * 64;
  float vmax = -INFINITY, vmin = INFINITY;
  for (int j = q; j < 256; j += 4) {
    float v = base[j * 64 + d];
    vmax = fmaxf(vmax, v);
    vmin = fminf(vmin, v);
  }
  smax[q][d] = vmax;
  smin[q][d] = vmin;
  __syncthreads();
  if (t < 64) {
    float mx = fmaxf(fmaxf(smax[0][t], smax[1][t]), fmaxf(smax[2][t], smax[3][t]));
    float mn = fminf(fminf(smin[0][t], smin[1][t]), fminf(smin[2][t], smin[3][t]));
    cat1[t] = emb1[bi * 64 + t];
    cat1[64 + t] = mx;
    cat1[128 + t] = mn;
  }
  __syncthreads();
  if (t < 128) {
    float acc = b1a[t];
    for (int k = 0; k < 192; ++k) acc += cat1[k] * W1a[k * 128 + t];
    h[t] = fmaxf(acc, 0.f);
  }
  __syncthreads();
  if (t < 64) {
    float acc = b1b[t];
    for (int k = 0; k < 128; ++k) acc += h[k] * W1b[k * 64 + t];
    out1[bi * 64 + t] = acc;
  }
}

// ---------------------------------------------------------------------------
// out2: persistent block per (b,i) processing 4 j-tiles of 64 rows.
// X row r = [e1[b,j0+r] | emb2[b,j0+r,i] | emb2[b,i,j0+r]]  (192 bf16, 384B)
// GEMM1 (K=192, swapped): P^T = Wcat^T @ X^T
// epi:  H = relu(P + T2p[b,i,n])  (T2p covers e1[b,i]@Wa2 + b2a)
// GEMM2 (K=256, swapped): O^T = W2b^T @ H^T; + b2b
//
// LDS 80 KB: X double-buffer 2x24KB + H 32KB -> 2 blocks/CU.
// Per generation: {issue next-tile loads -> regs (T14) ; GEMM1 ; epi->H ;
//   stage_write Xnext ; lgkmcnt(0)+s_barrier ; GEMM2+store ; s_barrier}.
// NO vmcnt(0) drain in the loop; stage loads ride under GEMM1/epi.
// XOR swizzle byte ^= (row&7)<<4 on X and H.
// ---------------------------------------------------------------------------
__global__ __launch_bounds__(256, 2) void out2_kernel(
    const float* __restrict__ emb1, const float* __restrict__ emb2,
    const float* __restrict__ b2b,
    const u16* __restrict__ wfA, const u16* __restrict__ wfB,
    const float* __restrict__ T2p, float* __restrict__ out2) {
  __shared__ __align__(16) u16 SH[40960];  // X0 [0,12288) X1 [12288,24576) H [24576,40960)

  int blk = blockIdx.x;
  int b = blk >> 8;
  int i = blk & 255;
  int t = threadIdx.x;
  int lane = t & 63;
  int w = t >> 6;
  int lr = lane & 15;
  int lg = lane >> 4;

  u16* X0 = SH;
  u16* X1 = SH + 12288;
  u16* H = SH + 24576;
  char* Hb = (char*)SH + 49152;

  // hoisted per-block loads
  bf16x8 wb[8];
#pragma unroll
  for (int ks = 0; ks < 8; ++ks)
    wb[ks] = ld_frag_glb(wfB + (size_t)(((w << 3) + ks) * 64 + lane) * 8);
  float4 t2v[4];
#pragma unroll
  for (int nt = 0; nt < 4; ++nt)
    t2v[nt] = *(const float4*)(T2p + ((size_t)(b << 8) + i) * 256 +
                               (w << 6) + (nt << 4) + (lg << 2));
  float4 bias2 = *(const float4*)(b2b + (w << 4) + (lg << 2));
  float* oblk = out2 + (((size_t)(b << 8) + i) << 8) * 64 + (w << 4) + (lg << 2);

  // staging: thread covers row sr, 48 floats (3 chunks of 16) at sq*48
  int sr = t >> 2, sq = t & 3;
  float4 vs[12];

  auto stage_load = [&](int j0n) {
    const float* s0 = emb1 + (((b << 8) + j0n + sr) << 6);
    const float* s1 = emb2 + (((size_t)((b << 8) + j0n + sr) << 8) + i) * 64;
    const float* s2 = emb2 + (((size_t)((b << 8) + i) << 8) + (j0n + sr)) * 64;
#pragma unroll
    for (int ch = 0; ch < 3; ++ch) {
      int c = sq * 48 + ch * 16;
      int seg = c >> 6, off = c & 63;
      const float* src = (seg == 0 ? s0 : (seg == 1 ? s1 : s2)) + off;
#pragma unroll
      for (int u = 0; u < 4; ++u) vs[ch * 4 + u] = *(const float4*)(src + (u << 2));
    }
  };
  auto stage_write = [&](u16* Xn) {
    char* Xb = (char*)Xn;
    int swz = (sr & 7) << 4;
#pragma unroll
    for (int ch = 0; ch < 3; ++ch) {
      int cb = (sq * 48 + ch * 16) * 2;
      float4 a0 = vs[ch * 4 + 0], a1 = vs[ch * 4 + 1];
      float4 a2 = vs[ch * 4 + 2], a3 = vs[ch * 4 + 3];
      u16x8 o0 = {cvt_bf16(a0.x), cvt_bf16(a0.y), cvt_bf16(a0.z), cvt_bf16(a0.w),
                  cvt_bf16(a1.x), cvt_bf16(a1.y), cvt_bf16(a1.z), cvt_bf16(a1.w)};
      u16x8 o1 = {cvt_bf16(a2.x), cvt_bf16(a2.y), cvt_bf16(a2.z), cvt_bf16(a2.w),
                  cvt_bf16(a3.x), cvt_bf16(a3.y), cvt_bf16(a3.z), cvt_bf16(a3.w)};
      *(u16x8*)(Xb + ((sr * 384 + cb) ^ swz)) = o0;
      *(u16x8*)(Xb + ((sr * 384 + cb + 16) ^ swz)) = o1;
    }
  };

  // prologue: fill X0
  stage_load(0);
  stage_write(X0);
  __syncthreads();

#pragma unroll
  for (int g = 0; g < 4; ++g) {
    int j0 = g << 6;
    u16* Xc = (g & 1) ? X1 : X0;
    u16* Xn = (g & 1) ? X0 : X1;

    if (g < 3) stage_load(j0 + 64);  // issue early; lands under GEMM1/epi

    // ---- GEMM1: K=192, wave w owns n in [w*64, w*64+64) ----
    f32x4 acc1[4][4];
#pragma unroll
    for (int m = 0; m < 4; ++m)
#pragma unroll
      for (int nt = 0; nt < 4; ++nt) acc1[m][nt] = (f32x4){0.f, 0.f, 0.f, 0.f};

#pragma unroll
    for (int ks = 0; ks < 6; ++ks) {
      int kByte = (ks << 6) + (lg << 4);
      bf16x8 a[4];
#pragma unroll
      for (int m = 0; m < 4; ++m) {
        int row = (m << 4) + lr;
        a[m] = ld_frag_lds(Xc, (row * 384 + kByte) ^ ((lr & 7) << 4));
      }
      bf16x8 bw[4];
#pragma unroll
      for (int nt = 0; nt < 4; ++nt)
        bw[nt] = ld_frag_glb(wfA + (size_t)((((w << 2) + nt) * 6 + ks) * 64 + lane) * 8);
#pragma unroll
      for (int m = 0; m < 4; ++m)
#pragma unroll
        for (int nt = 0; nt < 4; ++nt)
          acc1[m][nt] = __builtin_amdgcn_mfma_f32_16x16x32_bf16(bw[nt], a[m], acc1[m][nt], 0, 0, 0);
    }

    // ---- epi: H = relu(P + T2p); acc1[m][nt][e]: j=m*16+lr, n=w*64+nt*16+lg*4+e ----
#pragma unroll
    for (int nt = 0; nt < 4; ++nt) {
      int n_lo = (((w << 2) + nt) << 4) + (lg << 2);
#pragma unroll
      for (int m = 0; m < 4; ++m) {
        int jrow = (m << 4) + lr;
        u16x4 o = {cvt_bf16(fmaxf(acc1[m][nt][0] + t2v[nt].x, 0.f)),
                   cvt_bf16(fmaxf(acc1[m][nt][1] + t2v[nt].y, 0.f)),
                   cvt_bf16(fmaxf(acc1[m][nt][2] + t2v[nt].z, 0.f)),
                   cvt_bf16(fmaxf(acc1[m][nt][3] + t2v[nt].w, 0.f))};
        *(u16x4*)(Hb + ((jrow * 512 + n_lo * 2) ^ ((lr & 7) << 4))) = o;
      }
    }

    if (g < 3) stage_write(Xn);  // write-late: Xn not read until next gen

    asm volatile("s_waitcnt lgkmcnt(0)");   // H (and Xn) writes complete
    __builtin_amdgcn_s_barrier();           // barB: H visible to all waves
    __builtin_amdgcn_sched_barrier(0);

    // ---- GEMM2: K=256, wave w owns d in [w*16, w*16+16) ----
    f32x4 acc2[4];
#pragma unroll
    for (int jt = 0; jt < 4; ++jt) acc2[jt] = (f32x4){0.f, 0.f, 0.f, 0.f};

#pragma unroll
    for (int ks = 0; ks < 8; ++ks) {
      int kByte = (ks << 6) + (lg << 4);
#pragma unroll
      for (int jt = 0; jt < 4; ++jt) {
        int row = (jt << 4) + lr;
        bf16x8 hfr = ld_frag_lds(H, (row * 512 + kByte) ^ ((lr & 7) << 4));
        acc2[jt] = __builtin_amdgcn_mfma_f32_16x16x32_bf16(wb[ks], hfr, acc2[jt], 0, 0, 0);
      }
    }

    // ---- store: acc2[jt][e]: j=jt*16+lr, d=w*16+lg*4+e ----
    float* obase = oblk + (size_t)j0 * 64;
#pragma unroll
    for (int jt = 0; jt < 4; ++jt) {
      float4 v = {acc2[jt][0] + bias2.x, acc2[jt][1] + bias2.y,
                  acc2[jt][2] + bias2.z, acc2[jt][3] + bias2.w};
      *(float4*)(obase + (size_t)((jt << 4) + lr) * 64) = v;
    }

    __builtin_amdgcn_s_barrier();           // barC: H reads done before next epi
    __builtin_amdgcn_sched_barrier(0);
  }
}

extern "C" void kernel_launch(void* const* d_in, const int* in_sizes, int n_in,
                              void* d_out, int out_size, void* d_ws, size_t ws_size,
                              hipStream_t stream) {
  const float* emb1 = (const float*)d_in[0];
  const float* emb2 = (const float*)d_in[1];
  const float* W1a  = (const float*)d_in[2];
  const float* b1a  = (const float*)d_in[3];
  const float* W1b  = (const float*)d_in[4];
  const float* b1b  = (const float*)d_in[5];
  const float* W2a  = (const float*)d_in[6];
  const float* b2a  = (const float*)d_in[7];
  const float* W2b  = (const float*)d_in[8];
  const float* b2b  = (const float*)d_in[9];

  float* out = (float*)d_out;
  u16* wfA = (u16*)d_ws;                 // 16*6*64*8 = 49152 u16 = 96 KB
  u16* wfB = wfA + 49152;                // 16384 u16 = 32 KB
  float* T2p = (float*)(wfB + 16384);    // 2048*256 f32 = 2 MB

  prep_w_kernel<<<32, 256, 0, stream>>>(W2a, W2b, wfA, wfB);
  prep_T2_kernel<<<2048, 256, 0, stream>>>(emb1, W2a, b2a, T2p);
  // out1 first: its sequential emb2 read warms L3 for out2's gathers
  out1_kernel<<<2048, 256, 0, stream>>>(emb1, emb2, W1a, b1a, W1b, b1b, out);
  out2_kernel<<<2048, 256, 0, stream>>>(emb1, emb2, b2b, wfA, wfB, T2p,
                                        out + 8 * 256 * 64);
}

// Round 9
// 256.651 us; speedup vs baseline: 1.0096x; 1.0096x over previous
//
#include <hip/hip_runtime.h>
#include <hip/hip_bf16.h>

typedef __bf16 bf16x8 __attribute__((ext_vector_type(8)));
typedef float f32x4 __attribute__((ext_vector_type(4)));
typedef unsigned int u32;
typedef unsigned short u16;
typedef u32 u32x4 __attribute__((ext_vector_type(4)));
typedef u16 u16x4 __attribute__((ext_vector_type(4)));
typedef u16 u16x8 __attribute__((ext_vector_type(8)));

// manual RNE f32->bf16 (prep kernels)
__device__ __forceinline__ u16 f2bf(float x) {
  u32 u = __float_as_uint(x);
  return (u16)((u + 0x7FFFu + ((u >> 16) & 1u)) >> 16);
}
// compiler cast (hot path; lowers to v_cvt_pk_bf16_f32)
__device__ __forceinline__ u16 cvt_bf16(float x) {
  __bf16 h = (__bf16)x;
  return __builtin_bit_cast(u16, h);
}

__device__ __forceinline__ bf16x8 ld_frag_lds(const u16* base, int byteOff) {
  u32x4 v = *(const u32x4*)((const char*)base + byteOff);
  return __builtin_bit_cast(bf16x8, v);
}
__device__ __forceinline__ bf16x8 ld_frag_glb(const u16* p) {
  u32x4 v = *(const u32x4*)p;
  return __builtin_bit_cast(bf16x8, v);
}

// ---------------------------------------------------------------------------
// prep_w: bf16 MFMA A-operand (weight) fragments.
// wfA: Wcat = [W2a rows 0:64 (e1j) ; 64:128 (E2[j,i]) ; 192:256 (E2[i,j])]
//      K=192, N=256: wfA[((ntg*6+ks)*64+lane)*8+q] =
//        Wcat[ks*32+(lane>>4)*8+q][ntg*16+(lane&15)]
// wfB: W2b K=256 N=64: wfB[((ntg*8+ks)*64+lane)*8+q] likewise.
// ---------------------------------------------------------------------------
__global__ void prep_w_kernel(const float* __restrict__ W2a, const float* __restrict__ W2b,
                              u16* __restrict__ wfA, u16* __restrict__ wfB) {
  int t = blockIdx.x * 256 + threadIdx.x;
  if (t < 6144) {  // 16 ntg * 6 ks * 64 lanes
    int lane = t & 63;
    int ks = (t >> 6) % 6;
    int ntg = t / 384;
    int col = (ntg << 4) + (lane & 15);
    int kk = (ks << 5) + ((lane >> 4) << 3);
    int row = kk + (kk >= 128 ? 64 : 0);  // skip Wa2 rows 128:192 (handled by T2')
#pragma unroll
    for (int q = 0; q < 8; ++q)
      wfA[t * 8 + q] = f2bf(W2a[(row + q) * 256 + col]);
  } else if (t < 8192) {  // 4 ntg * 8 ks * 64 lanes
    int t2 = t - 6144;
    int lane = t2 & 63;
    int ks = (t2 >> 6) & 7;
    int ntg = t2 >> 9;
    int col = (ntg << 4) + (lane & 15);
    int k = (ks << 5) + ((lane >> 4) << 3);
#pragma unroll
    for (int q = 0; q < 8; ++q)
      wfB[t2 * 8 + q] = f2bf(W2b[(k + q) * 64 + col]);
  }
}

// ---------------------------------------------------------------------------
// prep_T2: T2p[b,i,n] = e1[b,i] @ W2a[128:192] + b2a[n]   (f32, 2 MB)
// ---------------------------------------------------------------------------
__global__ __launch_bounds__(256) void prep_T2_kernel(
    const float* __restrict__ emb1, const float* __restrict__ W2a,
    const float* __restrict__ b2a, float* __restrict__ T2p) {
  __shared__ float e1row[64];
  int bn = blockIdx.x;
  int t = threadIdx.x;
  if (t < 64) e1row[t] = emb1[bn * 64 + t];
  __syncthreads();
  float a = b2a[t];
#pragma unroll 8
  for (int k = 0; k < 64; ++k) a += e1row[k] * W2a[(128 + k) * 256 + t];
  T2p[(size_t)bn * 256 + t] = a;
}

// ---------------------------------------------------------------------------
// out1: R1-proven. One block per (b,i). Also serves to pre-warm emb2 into L3
// before out2's scattered gathers (launched first).
// ---------------------------------------------------------------------------
__global__ __launch_bounds__(256) void out1_kernel(
    const float* __restrict__ emb1, const float* __restrict__ emb2,
    const float* __restrict__ W1a, const float* __restrict__ b1a,
    const float* __restrict__ W1b, const float* __restrict__ b1b,
    float* __restrict__ out1) {
  int bi = blockIdx.x;
  int t = threadIdx.x;
  __shared__ float smax[4][64];
  __shared__ float smin[4][64];
  __shared__ float cat1[192];
  __shared__ float h[128];

  int d = t & 63, q = t >> 6;
  const float* base = emb2 + (size_t)bi * 256 * 64;
  float vmax = -INFINITY, vmin = INFINITY;
  for (int j = q; j < 256; j += 4) {
    float v = base[j * 64 + d];
    vmax = fmaxf(vmax, v);
    vmin = fminf(vmin, v);
  }
  smax[q][d] = vmax;
  smin[q][d] = vmin;
  __syncthreads();
  if (t < 64) {
    float mx = fmaxf(fmaxf(smax[0][t], smax[1][t]), fmaxf(smax[2][t], smax[3][t]));
    float mn = fminf(fminf(smin[0][t], smin[1][t]), fminf(smin[2][t], smin[3][t]));
    cat1[t] = emb1[bi * 64 + t];
    cat1[64 + t] = mx;
    cat1[128 + t] = mn;
  }
  __syncthreads();
  if (t < 128) {
    float acc = b1a[t];
    for (int k = 0; k < 192; ++k) acc += cat1[k] * W1a[k * 128 + t];
    h[t] = fmaxf(acc, 0.f);
  }
  __syncthreads();
  if (t < 64) {
    float acc = b1b[t];
    for (int k = 0; k < 128; ++k) acc += h[k] * W1b[k * 64 + t];
    out1[bi * 64 + t] = acc;
  }
}

// ---------------------------------------------------------------------------
// out2: persistent block per (b,i) processing 4 j-tiles of 64 rows.
// X row r = [e1[b,j0+r] | emb2[b,j0+r,i] | emb2[b,i,j0+r]]  (192 bf16, 384B)
// GEMM1 (K=192, swapped): P^T = Wcat^T @ X^T
// epi:  H = relu(P + T2p[b,i,n])  (T2p covers e1[b,i]@Wa2 + b2a)
// GEMM2 (K=256, swapped): O^T = W2b^T @ H^T; + b2b
//
// LDS 80 KB: X double-buffer 2x24KB + H 32KB -> 2 blocks/CU.
// Per generation: {issue next-tile loads -> regs (T14) ; GEMM1 ; epi->H ;
//   stage_write Xnext ; lgkmcnt(0)+s_barrier ; GEMM2+store ; s_barrier}.
// NO vmcnt(0) drain in the loop; stage loads ride under GEMM1/epi.
// XOR swizzle byte ^= (row&7)<<4 on X and H.
// ---------------------------------------------------------------------------
__global__ __launch_bounds__(256, 2) void out2_kernel(
    const float* __restrict__ emb1, const float* __restrict__ emb2,
    const float* __restrict__ b2b,
    const u16* __restrict__ wfA, const u16* __restrict__ wfB,
    const float* __restrict__ T2p, float* __restrict__ out2) {
  __shared__ __align__(16) u16 SH[40960];  // X0 [0,12288) X1 [12288,24576) H [24576,40960)

  int blk = blockIdx.x;
  int b = blk >> 8;
  int i = blk & 255;
  int t = threadIdx.x;
  int lane = t & 63;
  int w = t >> 6;
  int lr = lane & 15;
  int lg = lane >> 4;

  u16* X0 = SH;
  u16* X1 = SH + 12288;
  u16* H = SH + 24576;
  char* Hb = (char*)SH + 49152;

  // hoisted per-block loads
  bf16x8 wb[8];
#pragma unroll
  for (int ks = 0; ks < 8; ++ks)
    wb[ks] = ld_frag_glb(wfB + (size_t)(((w << 3) + ks) * 64 + lane) * 8);
  float4 t2v[4];
#pragma unroll
  for (int nt = 0; nt < 4; ++nt)
    t2v[nt] = *(const float4*)(T2p + ((size_t)(b << 8) + i) * 256 +
                               (w << 6) + (nt << 4) + (lg << 2));
  float4 bias2 = *(const float4*)(b2b + (w << 4) + (lg << 2));
  float* oblk = out2 + (((size_t)(b << 8) + i) << 8) * 64 + (w << 4) + (lg << 2);

  // staging: thread covers row sr, 48 floats (3 chunks of 16) at sq*48
  int sr = t >> 2, sq = t & 3;
  float4 vs[12];

  auto stage_load = [&](int j0n) {
    const float* s0 = emb1 + (((b << 8) + j0n + sr) << 6);
    const float* s1 = emb2 + (((size_t)((b << 8) + j0n + sr) << 8) + i) * 64;
    const float* s2 = emb2 + (((size_t)((b << 8) + i) << 8) + (j0n + sr)) * 64;
#pragma unroll
    for (int ch = 0; ch < 3; ++ch) {
      int c = sq * 48 + ch * 16;
      int seg = c >> 6, off = c & 63;
      const float* src = (seg == 0 ? s0 : (seg == 1 ? s1 : s2)) + off;
#pragma unroll
      for (int u = 0; u < 4; ++u) vs[ch * 4 + u] = *(const float4*)(src + (u << 2));
    }
  };
  auto stage_write = [&](u16* Xn) {
    char* Xb = (char*)Xn;
    int swz = (sr & 7) << 4;
#pragma unroll
    for (int ch = 0; ch < 3; ++ch) {
      int cb = (sq * 48 + ch * 16) * 2;
      float4 a0 = vs[ch * 4 + 0], a1 = vs[ch * 4 + 1];
      float4 a2 = vs[ch * 4 + 2], a3 = vs[ch * 4 + 3];
      u16x8 o0 = {cvt_bf16(a0.x), cvt_bf16(a0.y), cvt_bf16(a0.z), cvt_bf16(a0.w),
                  cvt_bf16(a1.x), cvt_bf16(a1.y), cvt_bf16(a1.z), cvt_bf16(a1.w)};
      u16x8 o1 = {cvt_bf16(a2.x), cvt_bf16(a2.y), cvt_bf16(a2.z), cvt_bf16(a2.w),
                  cvt_bf16(a3.x), cvt_bf16(a3.y), cvt_bf16(a3.z), cvt_bf16(a3.w)};
      *(u16x8*)(Xb + ((sr * 384 + cb) ^ swz)) = o0;
      *(u16x8*)(Xb + ((sr * 384 + cb + 16) ^ swz)) = o1;
    }
  };

  // prologue: fill X0
  stage_load(0);
  stage_write(X0);
  __syncthreads();

#pragma unroll
  for (int g = 0; g < 4; ++g) {
    int j0 = g << 6;
    u16* Xc = (g & 1) ? X1 : X0;
    u16* Xn = (g & 1) ? X0 : X1;

    if (g < 3) stage_load(j0 + 64);  // issue early; lands under GEMM1/epi

    // ---- GEMM1: K=192, wave w owns n in [w*64, w*64+64) ----
    f32x4 acc1[4][4];
#pragma unroll
    for (int m = 0; m < 4; ++m)
#pragma unroll
      for (int nt = 0; nt < 4; ++nt) acc1[m][nt] = (f32x4){0.f, 0.f, 0.f, 0.f};

#pragma unroll
    for (int ks = 0; ks < 6; ++ks) {
      int kByte = (ks << 6) + (lg << 4);
      bf16x8 a[4];
#pragma unroll
      for (int m = 0; m < 4; ++m) {
        int row = (m << 4) + lr;
        a[m] = ld_frag_lds(Xc, (row * 384 + kByte) ^ ((lr & 7) << 4));
      }
      bf16x8 bw[4];
#pragma unroll
      for (int nt = 0; nt < 4; ++nt)
        bw[nt] = ld_frag_glb(wfA + (size_t)((((w << 2) + nt) * 6 + ks) * 64 + lane) * 8);
#pragma unroll
      for (int m = 0; m < 4; ++m)
#pragma unroll
        for (int nt = 0; nt < 4; ++nt)
          acc1[m][nt] = __builtin_amdgcn_mfma_f32_16x16x32_bf16(bw[nt], a[m], acc1[m][nt], 0, 0, 0);
    }

    // ---- epi: H = relu(P + T2p); acc1[m][nt][e]: j=m*16+lr, n=w*64+nt*16+lg*4+e ----
#pragma unroll
    for (int nt = 0; nt < 4; ++nt) {
      int n_lo = (((w << 2) + nt) << 4) + (lg << 2);
#pragma unroll
      for (int m = 0; m < 4; ++m) {
        int jrow = (m << 4) + lr;
        u16x4 o = {cvt_bf16(fmaxf(acc1[m][nt][0] + t2v[nt].x, 0.f)),
                   cvt_bf16(fmaxf(acc1[m][nt][1] + t2v[nt].y, 0.f)),
                   cvt_bf16(fmaxf(acc1[m][nt][2] + t2v[nt].z, 0.f)),
                   cvt_bf16(fmaxf(acc1[m][nt][3] + t2v[nt].w, 0.f))};
        *(u16x4*)(Hb + ((jrow * 512 + n_lo * 2) ^ ((lr & 7) << 4))) = o;
      }
    }

    if (g < 3) stage_write(Xn);  // write-late: Xn not read until next gen

    asm volatile("s_waitcnt lgkmcnt(0)");   // H (and Xn) writes complete
    __builtin_amdgcn_s_barrier();           // barB: H visible to all waves
    __builtin_amdgcn_sched_barrier(0);

    // ---- GEMM2: K=256, wave w owns d in [w*16, w*16+16) ----
    f32x4 acc2[4];
#pragma unroll
    for (int jt = 0; jt < 4; ++jt) acc2[jt] = (f32x4){0.f, 0.f, 0.f, 0.f};

#pragma unroll
    for (int ks = 0; ks < 8; ++ks) {
      int kByte = (ks << 6) + (lg << 4);
#pragma unroll
      for (int jt = 0; jt < 4; ++jt) {
        int row = (jt << 4) + lr;
        bf16x8 hfr = ld_frag_lds(H, (row * 512 + kByte) ^ ((lr & 7) << 4));
        acc2[jt] = __builtin_amdgcn_mfma_f32_16x16x32_bf16(wb[ks], hfr, acc2[jt], 0, 0, 0);
      }
    }

    // ---- store: acc2[jt][e]: j=jt*16+lr, d=w*16+lg*4+e ----
    float* obase = oblk + (size_t)j0 * 64;
#pragma unroll
    for (int jt = 0; jt < 4; ++jt) {
      float4 v = {acc2[jt][0] + bias2.x, acc2[jt][1] + bias2.y,
                  acc2[jt][2] + bias2.z, acc2[jt][3] + bias2.w};
      *(float4*)(obase + (size_t)((jt << 4) + lr) * 64) = v;
    }

    __builtin_amdgcn_s_barrier();           // barC: H reads done before next epi
    __builtin_amdgcn_sched_barrier(0);
  }
}

extern "C" void kernel_launch(void* const* d_in, const int* in_sizes, int n_in,
                              void* d_out, int out_size, void* d_ws, size_t ws_size,
                              hipStream_t stream) {
  const float* emb1 = (const float*)d_in[0];
  const float* emb2 = (const float*)d_in[1];
  const float* W1a  = (const float*)d_in[2];
  const float* b1a  = (const float*)d_in[3];
  const float* W1b  = (const float*)d_in[4];
  const float* b1b  = (const float*)d_in[5];
  const float* W2a  = (const float*)d_in[6];
  const float* b2a  = (const float*)d_in[7];
  const float* W2b  = (const float*)d_in[8];
  const float* b2b  = (const float*)d_in[9];

  float* out = (float*)d_out;
  u16* wfA = (u16*)d_ws;                 // 16*6*64*8 = 49152 u16 = 96 KB
  u16* wfB = wfA + 49152;                // 16384 u16 = 32 KB
  float* T2p = (float*)(wfB + 16384);    // 2048*256 f32 = 2 MB

  prep_w_kernel<<<32, 256, 0, stream>>>(W2a, W2b, wfA, wfB);
  prep_T2_kernel<<<2048, 256, 0, stream>>>(emb1, W2a, b2a, T2p);
  // out1 first: its sequential emb2 read warms L3 for out2's gathers
  out1_kernel<<<2048, 256, 0, stream>>>(emb1, emb2, W1a, b1a, W1b, b1b, out);
  out2_kernel<<<2048, 256, 0, stream>>>(emb1, emb2, b2b, wfA, wfB, T2p,
                                        out + 8 * 256 * 64);
}

// Round 10
// 152.564 us; speedup vs baseline: 1.6984x; 1.6823x over previous
//
#include <hip/hip_runtime.h>
#include <hip/hip_bf16.h>

typedef __bf16 bf16x8 __attribute__((ext_vector_type(8)));
typedef float f32x4 __attribute__((ext_vector_type(4)));
typedef unsigned int u32;
typedef unsigned short u16;
typedef u32 u32x4 __attribute__((ext_vector_type(4)));
typedef u16 u16x4 __attribute__((ext_vector_type(4)));
typedef u16 u16x8 __attribute__((ext_vector_type(8)));

// manual RNE f32->bf16 (prep kernels)
__device__ __forceinline__ u16 f2bf(float x) {
  u32 u = __float_as_uint(x);
  return (u16)((u + 0x7FFFu + ((u >> 16) & 1u)) >> 16);
}
// compiler cast (hot path)
__device__ __forceinline__ u16 cvt_bf16(float x) {
  __bf16 h = (__bf16)x;
  return __builtin_bit_cast(u16, h);
}

__device__ __forceinline__ bf16x8 ld_frag_lds(const u16* base, int byteOff) {
  u32x4 v = *(const u32x4*)((const char*)base + byteOff);
  return __builtin_bit_cast(bf16x8, v);
}
__device__ __forceinline__ bf16x8 ld_frag_glb(const u16* p) {
  u32x4 v = *(const u32x4*)p;
  return __builtin_bit_cast(bf16x8, v);
}

// ---------------------------------------------------------------------------
// prep_w:
// wfA (128 KB): R1-proven layout, W2a K=256 N=256 as MFMA A-fragments:
//   wfA[((ntg*8+ks)*64+lane)*8+q] = W2a[ks*32+(lane>>4)*8+q][ntg*16+(lane&15)]
// wfB2 (32 KB): W2b fragments with the PI-PERMUTED k-order so GEMM1's acc1
//   feeds GEMM2's B-operand directly from registers. For wave w, k-step t2,
//   d-tile dt:  element (lane(c,g), q) = W2b[n][dt*16+c],
//   n = 64*w + 32*t2 + pi(g,q),  pi(g,q) = q<4 ? 4g+q : 16+4g+(q-4).
//   (pi is a bijection onto [0,32); A and B use the same permutation, so the
//    MFMA dot-product is exact — same principle as all prior k-maps.)
// ---------------------------------------------------------------------------
__global__ void prep_w_kernel(const float* __restrict__ W2a, const float* __restrict__ W2b,
                              u16* __restrict__ wfA, u16* __restrict__ wfB2) {
  int t = blockIdx.x * 256 + threadIdx.x;
  if (t < 8192) {  // wfA: 16 ntg * 8 ks * 64 lanes
    int lane = t & 63;
    int ks = (t >> 6) & 7;
    int ntg = t >> 9;
    int col = (ntg << 4) + (lane & 15);
    int kb = (ks << 5) + ((lane >> 4) << 3);
#pragma unroll
    for (int q = 0; q < 8; ++q)
      wfA[t * 8 + q] = f2bf(W2a[(kb + q) * 256 + col]);
  } else if (t < 10240) {  // wfB2: 4 w * 2 t2 * 4 dt * 64 lanes
    int t2i = t - 8192;  // 0..2047
    int lane = t2i & 63;
    int dt = (t2i >> 6) & 3;
    int tt = (t2i >> 8) & 1;
    int w = t2i >> 9;
    int g = lane >> 4, c = lane & 15;
    int col = (dt << 4) + c;
#pragma unroll
    for (int q = 0; q < 8; ++q) {
      int pi = (q < 4) ? (g * 4 + q) : (16 + g * 4 + (q - 4));
      int n = w * 64 + tt * 32 + pi;
      wfB2[t2i * 8 + q] = f2bf(W2b[n * 64 + col]);
    }
  }
}

// ---------------------------------------------------------------------------
// out1: R1-proven. One block per (b,i). Launched before out2 (L3 warm).
// ---------------------------------------------------------------------------
__global__ __launch_bounds__(256) void out1_kernel(
    const float* __restrict__ emb1, const float* __restrict__ emb2,
    const float* __restrict__ W1a, const float* __restrict__ b1a,
    const float* __restrict__ W1b, const float* __restrict__ b1b,
    float* __restrict__ out1) {
  int bi = blockIdx.x;
  int t = threadIdx.x;
  __shared__ float smax[4][64];
  __shared__ float smin[4][64];
  __shared__ float cat1[192];
  __shared__ float h[128];

  int d = t & 63, q = t >> 6;
  const float* base = emb2 + (size_t)bi * 256 * 64;
  float vmax = -INFINITY, vmin = INFINITY;
  for (int j = q; j < 256; j += 4) {
    float v = base[j * 64 + d];
    vmax = fmaxf(vmax, v);
    vmin = fminf(vmin, v);
  }
  smax[q][d] = vmax;
  smin[q][d] = vmin;
  __syncthreads();
  if (t < 64) {
    float mx = fmaxf(fmaxf(smax[0][t], smax[1][t]), fmaxf(smax[2][t], smax[3][t]));
    float mn = fminf(fminf(smin[0][t], smin[1][t]), fminf(smin[2][t], smin[3][t]));
    cat1[t] = emb1[bi * 64 + t];
    cat1[64 + t] = mx;
    cat1[128 + t] = mn;
  }
  __syncthreads();
  if (t < 128) {
    float acc = b1a[t];
    for (int k = 0; k < 192; ++k) acc += cat1[k] * W1a[k * 128 + t];
    h[t] = fmaxf(acc, 0.f);
  }
  __syncthreads();
  if (t < 64) {
    float acc = b1b[t];
    for (int k = 0; k < 128; ++k) acc += h[k] * W1b[k * 64 + t];
    out1[bi * 64 + t] = acc;
  }
}

// ---------------------------------------------------------------------------
// out2: one block = (b, i, j-tile of 64) — R1's proven grid/order (low FETCH).
// stage X -> bar -> GEMM1 (swapped, K=256) -> bar(X free) ->
//   GEMM2 ENTIRELY IN REGISTERS (relu(acc1+b2a) -> pi-packed bf16x8 B-frags x
//   pi-permuted wfB2 A-frags; each wave = partial O over its 64-n slice) ->
//   write 12 f32x4 partial tiles to LDS -> bar -> add 3 peers' tiles -> store.
// No H buffer, no H bank conflicts, no lgkm-heavy mid drain.
// LDS 48 KB (X 32 KB reused by the 48 KB exchange region).
// __launch_bounds__(256,2): proven no-spill envelope (VGPR cap 256).
// ---------------------------------------------------------------------------
__global__ __launch_bounds__(256, 2) void out2_kernel(
    const float* __restrict__ emb1, const float* __restrict__ emb2,
    const float* __restrict__ b2a, const float* __restrict__ b2b,
    const u16* __restrict__ wfA, const u16* __restrict__ wfB2,
    float* __restrict__ out2) {
  __shared__ __align__(16) u16 SH[24576];  // 48 KB

  int blk = blockIdx.x;
  int b = blk >> 10;
  int i = (blk >> 2) & 255;
  int j0 = (blk & 3) << 6;
  int t = threadIdx.x;
  int lane = t & 63;
  int w = t >> 6;
  int lr = lane & 15;
  int lg = lane >> 4;

  // ---- stage X: 64 rows x 256 bf16 (512B rows), swizzle byte^=(r&7)<<4 ----
  {
    int r = t >> 2;
    int c16 = (t & 3) << 4;
    const float* s0 = emb1 + ((b << 8) + j0 + r) * 64;
    const float* s1 = emb2 + ((((size_t)(b << 8) + j0 + r) << 8) + i) * 64;
    const float* s2 = emb1 + ((b << 8) + i) * 64;
    const float* s3 = emb2 + ((((size_t)(b << 8) + i) << 8) + (j0 + r)) * 64;
    const float* srcs[4] = {s0, s1, s2, s3};
#pragma unroll
    for (int seg = 0; seg < 4; ++seg) {
      const float* src = srcs[seg];
#pragma unroll
      for (int u = 0; u < 2; ++u) {
        int d = c16 + (u << 3);
        float4 v0 = *(const float4*)(src + d);
        float4 v1 = *(const float4*)(src + d + 4);
        u16x8 o = {cvt_bf16(v0.x), cvt_bf16(v0.y), cvt_bf16(v0.z), cvt_bf16(v0.w),
                   cvt_bf16(v1.x), cvt_bf16(v1.y), cvt_bf16(v1.z), cvt_bf16(v1.w)};
        int byteOff = (r * 512 + ((seg << 6) + d) * 2) ^ ((r & 7) << 4);
        *(u16x8*)((char*)SH + byteOff) = o;
      }
    }
  }
  __syncthreads();

  // ---- GEMM1 (swapped): acc1[m][nt][e]: j = 16m+lr, n = 64w+16nt+4lg+e ----
  f32x4 acc1[4][4];
#pragma unroll
  for (int m = 0; m < 4; ++m)
#pragma unroll
    for (int nt = 0; nt < 4; ++nt) acc1[m][nt] = (f32x4){0.f, 0.f, 0.f, 0.f};

#pragma unroll
  for (int ks = 0; ks < 8; ++ks) {
    int kByte = (ks << 6) + (lg << 4);
    bf16x8 a[4];
#pragma unroll
    for (int m = 0; m < 4; ++m) {
      int row = (m << 4) + lr;
      a[m] = ld_frag_lds(SH, (row * 512 + kByte) ^ ((lr & 7) << 4));
    }
    bf16x8 bw[4];
#pragma unroll
    for (int nt = 0; nt < 4; ++nt)
      bw[nt] = ld_frag_glb(wfA + (size_t)((((w << 2) + nt) * 8 + ks) * 64 + lane) * 8);
#pragma unroll
    for (int m = 0; m < 4; ++m)
#pragma unroll
      for (int nt = 0; nt < 4; ++nt)
        acc1[m][nt] = __builtin_amdgcn_mfma_f32_16x16x32_bf16(bw[nt], a[m], acc1[m][nt], 0, 0, 0);
  }

  __syncthreads();  // all X reads done; SH becomes the exchange region

  // ---- GEMM2 in registers: wave w = partial O over n in [64w, 64w+64) ----
  // h8 elem q<4 = relu(acc1[m][2t2][q]  + b2a[64w+32t2+4lg+q])      (n = ..+4lg+q)
  //      q>=4  = relu(acc1[m][2t2+1][q-4]+b2a[64w+32t2+16+4lg+q-4])  (n = ..+16+4lg+..)
  // wfB2 uses the same pi-order, so slot-k pairing is consistent.
  f32x4 acc2[4][4];  // [m][dt] partials, d = 16dt+4lg+e, j = 16m+lr
#pragma unroll
  for (int m = 0; m < 4; ++m)
#pragma unroll
    for (int dt = 0; dt < 4; ++dt) acc2[m][dt] = (f32x4){0.f, 0.f, 0.f, 0.f};

#pragma unroll
  for (int t2 = 0; t2 < 2; ++t2) {
    int nbase = (w << 6) + (t2 << 5) + (lg << 2);
    float4 ba = *(const float4*)(b2a + nbase);
    float4 bb = *(const float4*)(b2a + nbase + 16);
    bf16x8 h[4];
#pragma unroll
    for (int m = 0; m < 4; ++m) {
      f32x4 pa = acc1[m][2 * t2];
      f32x4 pb = acc1[m][2 * t2 + 1];
      u16x8 hp = {cvt_bf16(fmaxf(pa[0] + ba.x, 0.f)), cvt_bf16(fmaxf(pa[1] + ba.y, 0.f)),
                  cvt_bf16(fmaxf(pa[2] + ba.z, 0.f)), cvt_bf16(fmaxf(pa[3] + ba.w, 0.f)),
                  cvt_bf16(fmaxf(pb[0] + bb.x, 0.f)), cvt_bf16(fmaxf(pb[1] + bb.y, 0.f)),
                  cvt_bf16(fmaxf(pb[2] + bb.z, 0.f)), cvt_bf16(fmaxf(pb[3] + bb.w, 0.f))};
      h[m] = __builtin_bit_cast(bf16x8, hp);
    }
#pragma unroll
    for (int dt = 0; dt < 4; ++dt) {
      bf16x8 wf = ld_frag_glb(wfB2 + (size_t)(((((w << 1) + t2) << 2) + dt) * 64 + lane) * 8);
#pragma unroll
      for (int m = 0; m < 4; ++m)
        acc2[m][dt] = __builtin_amdgcn_mfma_f32_16x16x32_bf16(wf, h[m], acc2[m][dt], 0, 0, 0);
    }
  }

  // ---- cross-wave reduction: write acc2[m][dt!=w] (12 tiles x 1KB, lane*16B
  //      conflict-free). slot s = dt - (dt>w). total 48 KB. ----
  char* red = (char*)SH;
#pragma unroll
  for (int dt = 0; dt < 4; ++dt) {
    if (dt != w) {
      int s = dt - (dt > w ? 1 : 0);
#pragma unroll
      for (int m = 0; m < 4; ++m)
        *(f32x4*)(red + ((((w * 3 + s) << 2) + m) << 10) + (lane << 4)) = acc2[m][dt];
    }
  }
  __syncthreads();

  // own tile (static-index select) + peers' partials
  f32x4 accO[4];
#pragma unroll
  for (int m = 0; m < 4; ++m) {
    accO[m] = acc2[m][0];
#pragma unroll
    for (int dt = 1; dt < 4; ++dt)
      if (w == dt) accO[m] = acc2[m][dt];
  }
#pragma unroll
  for (int wp = 0; wp < 4; ++wp) {
    if (wp != w) {
      int s = w - (w > wp ? 1 : 0);
#pragma unroll
      for (int m = 0; m < 4; ++m) {
        f32x4 p = *(const f32x4*)(red + ((((wp * 3 + s) << 2) + m) << 10) + (lane << 4));
        accO[m] += p;
      }
    }
  }

  // ---- store: j = j0+16m+lr, d = 16w+4lg+e ----
  float4 bias2 = *(const float4*)(b2b + (w << 4) + (lg << 2));
  float* obase = out2 + (((size_t)(b << 8) + i) * 256 + j0) * 64 + (w << 4) + (lg << 2);
#pragma unroll
  for (int m = 0; m < 4; ++m) {
    float4 v = {accO[m][0] + bias2.x, accO[m][1] + bias2.y,
                accO[m][2] + bias2.z, accO[m][3] + bias2.w};
    *(float4*)(obase + (size_t)((m << 4) + lr) * 64) = v;
  }
}

extern "C" void kernel_launch(void* const* d_in, const int* in_sizes, int n_in,
                              void* d_out, int out_size, void* d_ws, size_t ws_size,
                              hipStream_t stream) {
  const float* emb1 = (const float*)d_in[0];
  const float* emb2 = (const float*)d_in[1];
  const float* W1a  = (const float*)d_in[2];
  const float* b1a  = (const float*)d_in[3];
  const float* W1b  = (const float*)d_in[4];
  const float* b1b  = (const float*)d_in[5];
  const float* W2a  = (const float*)d_in[6];
  const float* b2a  = (const float*)d_in[7];
  const float* W2b  = (const float*)d_in[8];
  const float* b2b  = (const float*)d_in[9];

  float* out = (float*)d_out;
  u16* wfA  = (u16*)d_ws;            // 16*8*64*8 = 65536 u16 = 128 KB
  u16* wfB2 = wfA + 65536;           //  4*2*4*64*8 = 16384 u16 = 32 KB

  prep_w_kernel<<<40, 256, 0, stream>>>(W2a, W2b, wfA, wfB2);
  // out1 first: sequential emb2 read warms L3 for out2's gathers (R1 order)
  out1_kernel<<<2048, 256, 0, stream>>>(emb1, emb2, W1a, b1a, W1b, b1b, out);
  out2_kernel<<<8192, 256, 0, stream>>>(emb1, emb2, b2a, b2b, wfA, wfB2,
                                        out + 8 * 256 * 64);
}